// Round 10
// baseline (153.956 us; speedup 1.0000x reference)
//
#include <hip/hip_runtime.h>

#define NP   16
#define EDIM 64
#define HH   8
#define BB   2
#define LL   2048
#define SS   2048
#define TQ   64
#define TS   64
#define NQT  (LL / TQ)     // 32
#define NPAIR (NQT / 2)    // 16
#define LDP  72            // LDS row stride in bf16 (64 + 8 pad)

typedef __attribute__((ext_vector_type(8))) short bf16x8;
typedef __attribute__((ext_vector_type(4))) float f32x4;

__device__ __forceinline__ unsigned short f2bf(float f) {
    union { float ff; unsigned int i; } x; x.ff = f;
    unsigned int r = x.i + 0x7fffu + ((x.i >> 16) & 1u);   // RNE
    return (unsigned short)(r >> 16);
}
__device__ __forceinline__ unsigned short truncbf(float f) {
    union { float ff; unsigned int i; } x; x.ff = f;
    return (unsigned short)(x.i >> 16);                    // truncate (P only)
}
__device__ __forceinline__ unsigned int pk2(float a, float b) {
    return (unsigned int)f2bf(a) | ((unsigned int)f2bf(b) << 16);
}

// 16 fp32 (global) -> 16 bf16 (LDS), scaled
__device__ __forceinline__ void stage16s(const float* __restrict__ g, unsigned short* l, float sc) {
    const float4* gp = (const float4*)g;
    float4 v0 = gp[0], v1 = gp[1], v2 = gp[2], v3 = gp[3];
    uint4 w0, w1;
    w0.x = pk2(v0.x * sc, v0.y * sc); w0.y = pk2(v0.z * sc, v0.w * sc);
    w0.z = pk2(v1.x * sc, v1.y * sc); w0.w = pk2(v1.z * sc, v1.w * sc);
    w1.x = pk2(v2.x * sc, v2.y * sc); w1.y = pk2(v2.z * sc, v2.w * sc);
    w1.z = pk2(v3.x * sc, v3.y * sc); w1.w = pk2(v3.z * sc, v3.w * sc);
    ((uint4*)l)[0] = w0; ((uint4*)l)[1] = w1;
}

#define INV4PI 0.07957747154594767f   // sin(th/2) = v_sin(th * 1/(4pi))

// ---------------------------------------------------------------------------
// Kernel 1: quantum encoding -> qevb (bf16 [B,H,E,S]) + K -> Kb (bf16
// [B,H,S,E]). Round-3-proven shape: one thread per token, direct loads,
// no value staging. Block = 64 threads = 64 tokens of one (b,h).
// ---------------------------------------------------------------------------
__global__ __launch_bounds__(64)
void qev2_kernel(const float* __restrict__ values,  // [B,S,H,E]
                 const float* __restrict__ key,     // [B,S,H,E]
                 const float* __restrict__ Wang,    // [16,64]
                 const float* __restrict__ bang,    // [16]
                 const float* __restrict__ Wout,    // [64,12]
                 const float* __restrict__ bout,    // [64]
                 unsigned short* __restrict__ qevb, // [B,H,E,S]
                 unsigned short* __restrict__ Kb)   // [B,H,S,E]
{
    __shared__ float sW[NP * EDIM];
    __shared__ float sWo[EDIM * 12];
    __shared__ float sba[NP];
    __shared__ float sbo[EDIM];

    const int tid = threadIdx.x;
    const int s0  = blockIdx.x * 64;
    const int h   = blockIdx.y;
    const int b   = blockIdx.z;

#pragma unroll
    for (int i = 0; i < 4; i++) ((float4*)sW)[i * 64 + tid] = ((const float4*)Wang)[i * 64 + tid];
#pragma unroll
    for (int i = 0; i < 3; i++) ((float4*)sWo)[i * 64 + tid] = ((const float4*)Wout)[i * 64 + tid];
    if (tid < NP) sba[tid] = bang[tid];
    sbo[tid] = bout[tid];
    __syncthreads();

    // ---- angles: direct per-token loads (round-3-proven pattern) ----
    const float* vptr = values + ((size_t)(b * SS + s0 + tid) * HH + h) * EDIM;
    float ang[NP];
#pragma unroll
    for (int p = 0; p < NP; p++) ang[p] = sba[p];
#pragma unroll
    for (int c = 0; c < 16; c++) {
        float4 vv = ((const float4*)vptr)[c];
#pragma unroll
        for (int p = 0; p < NP; p++) {
            float a = ang[p];
            a = fmaf(sW[p * EDIM + c * 4 + 0], vv.x, a);
            a = fmaf(sW[p * EDIM + c * 4 + 1], vv.y, a);
            a = fmaf(sW[p * EDIM + c * 4 + 2], vv.z, a);
            a = fmaf(sW[p * EDIM + c * 4 + 3], vv.w, a);
            ang[p] = a;
        }
    }

    // ---- batch sin/cos (independent, pipelined) ----
    float sc[NP], cc[NP];
#pragma unroll
    for (int p = 0; p < NP; p++) {
        float u = ang[p] * INV4PI;
        sc[p] = __builtin_amdgcn_sinf(u);
        cc[p] = __builtin_amdgcn_cosf(u);
    }

    // ---- 4-qubit circuit ----
    float sr[16], si[16];
#pragma unroll
    for (int i = 0; i < 16; i++) { sr[i] = 0.f; si[i] = 0.f; }
    sr[0] = 1.f;

    auto RY = [&](int w, float s, float c) {
        const int bit = 8 >> w;
#pragma unroll
        for (int i = 0; i < 16; i++) {
            if (!(i & bit)) {
                const int j = i | bit;
                float a0r = sr[i], a0i = si[i], a1r = sr[j], a1i = si[j];
                sr[i] = c * a0r - s * a1r;  si[i] = c * a0i - s * a1i;
                sr[j] = s * a0r + c * a1r;  si[j] = s * a0i + c * a1i;
            }
        }
    };
    auto CRX = [&](int cw, int tw, float s, float c) {
        const int cbit = 8 >> cw, tbit = 8 >> tw;
#pragma unroll
        for (int i = 0; i < 16; i++) {
            if ((i & cbit) && !(i & tbit)) {
                const int j = i | tbit;
                float a0r = sr[i], a0i = si[i], a1r = sr[j], a1i = si[j];
                sr[i] =  c * a0r + s * a1i;  si[i] =  c * a0i - s * a1r;
                sr[j] =  s * a0i + c * a1r;  si[j] = -s * a0r + c * a1i;
            }
        }
    };

    RY(0, sc[0], cc[0]); RY(1, sc[1], cc[1]); RY(2, sc[2], cc[2]); RY(3, sc[3], cc[3]);
    CRX(3, 0, sc[4], cc[4]); CRX(2, 3, sc[5], cc[5]); CRX(1, 2, sc[6], cc[6]); CRX(0, 1, sc[7], cc[7]);
    RY(0, sc[8], cc[8]); RY(1, sc[9], cc[9]); RY(2, sc[10], cc[10]); RY(3, sc[11], cc[11]);
    CRX(3, 2, sc[12], cc[12]); CRX(0, 3, sc[13], cc[13]); CRX(1, 0, sc[14], cc[14]); CRX(2, 1, sc[15], cc[15]);

    float meas[12];
#pragma unroll
    for (int w = 0; w < 4; w++) {
        const int bit = 8 >> w;
        float pr = 0.f, pi = 0.f, z = 0.f;
#pragma unroll
        for (int i = 0; i < 16; i++) {
            if (!(i & bit)) {
                const int j = i | bit;
                pr += sr[i] * sr[j] + si[i] * si[j];
                pi += sr[i] * si[j] - si[i] * sr[j];
                z  += sr[i] * sr[i] + si[i] * si[i] - sr[j] * sr[j] - si[j] * si[j];
            }
        }
        meas[w] = 2.f * pr; meas[4 + w] = 2.f * pi; meas[8 + w] = z;
    }

    // ---- out-GEMV, e-blocked (16 independent chains), coalesced bf16 store ----
    unsigned short* ob = qevb + ((size_t)(b * HH + h) * EDIM) * SS + s0 + tid;
#pragma unroll
    for (int eb = 0; eb < 4; eb++) {
        float acc[16];
#pragma unroll
        for (int j = 0; j < 16; j++) acc[j] = sbo[eb * 16 + j];
#pragma unroll
        for (int mm = 0; mm < 12; mm++)
#pragma unroll
            for (int j = 0; j < 16; j++)
                acc[j] = fmaf(meas[mm], sWo[(eb * 16 + j) * 12 + mm], acc[j]);
#pragma unroll
        for (int j = 0; j < 16; j++)
            ob[(size_t)(eb * 16 + j) * SS] = f2bf(acc[j]);
    }

    // ---- K conversion, remapped lanes: reads 4x256B, writes 512B/inst ----
    const float* ks = key + ((size_t)b * SS * HH + h) * EDIM;
    unsigned short* kd = Kb + ((size_t)(b * HH + h) * SS + s0) * EDIM;
#pragma unroll
    for (int i = 0; i < 16; i++) {
        const int u   = i * 64 + tid;      // uint2 unit 0..1023
        const int row = u >> 4;            // 0..63
        const int ch  = u & 15;            // float4 chunk 0..15
        float4 v = *(const float4*)(ks + (size_t)(s0 + row) * HH * EDIM + ch * 4);
        uint2 w2; w2.x = pk2(v.x, v.y); w2.y = pk2(v.z, v.w);
        *(uint2*)&kd[row * EDIM + ch * 4] = w2;
    }
}

// ---------------------------------------------------------------------------
// Kernel 2: barrier-free MFMA flash attention. K/V fragments are read
// DIRECTLY from global bf16 (L1/L2-resident tiles) -- no LDS staging, no
// in-loop barriers. LDS holds only Qs (per pass) and Ps (wave-private P
// round-trip). No-max softmax (scores bounded); l via ones-column MFMA.
// One block per causal pair (qt = bx, 31-bx): 256 blocks, 33 tiles each.
// ---------------------------------------------------------------------------
__global__ __launch_bounds__(256)
void attn5_kernel(const float* __restrict__ qry,            // [B,L,H,E] fp32
                  const unsigned short* __restrict__ Kb,    // [B,H,S,E] bf16
                  const unsigned short* __restrict__ Vb,    // [B,H,E,S] bf16
                  float* __restrict__ out)                  // [B,L,H,E] fp32
{
    __shared__ unsigned short Qs[TQ * LDP];
    __shared__ unsigned short Ps[TQ * LDP];

    const int tid  = threadIdx.x;
    const int bx   = blockIdx.x;     // 0..15
    const int h    = blockIdx.y;
    const int b    = blockIdx.z;
    const int w    = tid >> 6;
    const int lane = tid & 63;
    const int ml   = lane & 15;
    const int quad = lane >> 4;
    const int srow = tid >> 2;
    const int sch  = tid & 3;

    const unsigned short* kbase = Kb + (size_t)(b * HH + h) * SS * EDIM;
    const unsigned short* vbase = Vb + (size_t)(b * HH + h) * EDIM * SS;

    // ones B-fragment (B[k][n] = (n==0)) for the row-sum MFMA
    const short onev = (ml == 0) ? (short)0x3F80 : (short)0;
    bf16x8 onesf = { onev, onev, onev, onev, onev, onev, onev, onev };

    for (int pass = 0; pass < 2; ++pass) {
        const int qt = pass ? (NQT - 1 - bx) : bx;
        const int q0 = qt * TQ;

        __syncthreads();   // prev pass fully done with Qs (waves drift freely)
        stage16s(qry + (((size_t)b * LL + q0 + srow) * HH + h) * EDIM + sch * 16,
                 &Qs[srow * LDP + sch * 16], 0.125f);
        __syncthreads();

        bf16x8 a0 = *(const bf16x8*)&Qs[(16 * w + ml) * LDP + quad * 8];
        bf16x8 a1 = *(const bf16x8*)&Qs[(16 * w + ml) * LDP + quad * 8 + 32];

        f32x4 oacc[4];
        f32x4 lacc = (f32x4)(0.f);
#pragma unroll
        for (int i = 0; i < 4; i++) oacc[i] = (f32x4)(0.f);

        for (int t = 0; t <= qt; ++t) {
            const int s0e = t * TS;

            // ---- K fragments direct from global (b128, L1/L2-hot) ----
            const unsigned short* kr = kbase + (size_t)(s0e + ml) * EDIM + quad * 8;
            f32x4 sac[4];
#pragma unroll
            for (int nt = 0; nt < 4; nt++) {
                bf16x8 b0 = *(const bf16x8*)(kr + nt * 16 * EDIM);
                bf16x8 b1 = *(const bf16x8*)(kr + nt * 16 * EDIM + 32);
                sac[nt] = __builtin_amdgcn_mfma_f32_16x16x32_bf16(a0, b0, (f32x4)(0.f), 0, 0, 0);
                sac[nt] = __builtin_amdgcn_mfma_f32_16x16x32_bf16(a1, b1, sac[nt], 0, 0, 0);
            }

            // ---- P = exp(s), causal mask -> 0, truncate-pack to bf16 ----
            const bool diag = (t == qt);
#pragma unroll
            for (int nt = 0; nt < 4; nt++)
#pragma unroll
                for (int r = 0; r < 4; r++) {
                    float p = __expf(sac[nt][r]);
                    if (diag && (16 * nt + ml > 16 * w + 4 * quad + r)) p = 0.f;
                    Ps[(16 * w + 4 * quad + r) * LDP + 16 * nt + ml] = truncbf(p);
                }

            // ---- wave-private LDS round-trip (in-order DS; no barrier) ----
            bf16x8 p0 = *(const bf16x8*)&Ps[(16 * w + ml) * LDP + quad * 8];
            bf16x8 p1 = *(const bf16x8*)&Ps[(16 * w + ml) * LDP + quad * 8 + 32];

            // ---- V fragments direct from global + PV + row-sum ----
            const unsigned short* vr = vbase + (size_t)ml * SS + s0e + quad * 8;
#pragma unroll
            for (int nt = 0; nt < 4; nt++) {
                bf16x8 v0 = *(const bf16x8*)(vr + (size_t)(nt * 16) * SS);
                bf16x8 v1 = *(const bf16x8*)(vr + (size_t)(nt * 16) * SS + 32);
                oacc[nt] = __builtin_amdgcn_mfma_f32_16x16x32_bf16(p0, v0, oacc[nt], 0, 0, 0);
                oacc[nt] = __builtin_amdgcn_mfma_f32_16x16x32_bf16(p1, v1, oacc[nt], 0, 0, 0);
            }
            lacc = __builtin_amdgcn_mfma_f32_16x16x32_bf16(p0, onesf, lacc, 0, 0, 0);
            lacc = __builtin_amdgcn_mfma_f32_16x16x32_bf16(p1, onesf, lacc, 0, 0, 0);
        }

        // ---- epilogue: l lives in col 0 (lane quad*16) ----
        float inv[4];
#pragma unroll
        for (int r = 0; r < 4; r++) {
            float ls = __shfl(lacc[r], lane & 48, 64);
            inv[r] = 1.f / ls;
        }
#pragma unroll
        for (int nt = 0; nt < 4; nt++)
#pragma unroll
            for (int r = 0; r < 4; r++) {
                const int row = q0 + 16 * w + 4 * quad + r;
                out[(((size_t)b * LL + row) * HH + h) * EDIM + 16 * nt + ml] = oacc[nt][r] * inv[r];
            }
    }
}

extern "C" void kernel_launch(void* const* d_in, const int* in_sizes, int n_in,
                              void* d_out, int out_size, void* d_ws, size_t ws_size,
                              hipStream_t stream)
{
    const float* qry  = (const float*)d_in[0];
    const float* key  = (const float*)d_in[1];
    const float* val  = (const float*)d_in[2];
    const float* Wang = (const float*)d_in[3];
    const float* bang = (const float*)d_in[4];
    const float* Wout = (const float*)d_in[5];
    const float* bout = (const float*)d_in[6];
    float* out = (float*)d_out;

    unsigned short* qevb = (unsigned short*)d_ws;                                             // 4 MB
    unsigned short* Kb   = (unsigned short*)((char*)d_ws + (size_t)BB * HH * EDIM * SS * 2);  // 4 MB

    (void)in_sizes; (void)n_in; (void)out_size; (void)ws_size;

    qev2_kernel<<<dim3(SS / 64, HH, BB), 64, 0, stream>>>(val, key, Wang, bang, Wout, bout, qevb, Kb);
    attn5_kernel<<<dim3(NPAIR, HH, BB), 256, 0, stream>>>(qry, Kb, qevb, out);
}

// Round 11
// 119.128 us; speedup vs baseline: 1.2924x; 1.2924x over previous
//
#include <hip/hip_runtime.h>

#define NP   16
#define EDIM 64
#define HH   8
#define BB   2
#define LL   2048
#define SS   2048
#define NQT  32
#define NPAIR 16
#define LDP  72            // LDS row stride in bf16 (64 + 8 pad)

typedef __attribute__((ext_vector_type(8))) short bf16x8;
typedef __attribute__((ext_vector_type(4))) float f32x4;

__device__ __forceinline__ float bf2f(unsigned int u) {
    union { unsigned int i; float f; } x; x.i = u << 16; return x.f;
}
__device__ __forceinline__ unsigned short f2bf(float f) {
    union { float ff; unsigned int i; } x; x.ff = f;
    unsigned int r = x.i + 0x7fffu + ((x.i >> 16) & 1u);
    return (unsigned short)(r >> 16);
}
__device__ __forceinline__ unsigned int pk2(float a, float b) {
    return (unsigned int)f2bf(a) | ((unsigned int)f2bf(b) << 16);
}
__device__ __forceinline__ unsigned int tpk2(float a, float b) {   // truncate-pack
    union { float f; unsigned int i; } xa, xb; xa.f = a; xb.f = b;
    return (xa.i >> 16) | (xb.i & 0xffff0000u);
}

// 16 fp32 (global) -> 16 bf16 (LDS), scaled
__device__ __forceinline__ void stage16s(const float* __restrict__ g, unsigned short* l, float sc) {
    const float4* gp = (const float4*)g;
    float4 v0 = gp[0], v1 = gp[1], v2 = gp[2], v3 = gp[3];
    uint4 w0, w1;
    w0.x = pk2(v0.x * sc, v0.y * sc); w0.y = pk2(v0.z * sc, v0.w * sc);
    w0.z = pk2(v1.x * sc, v1.y * sc); w0.w = pk2(v1.z * sc, v1.w * sc);
    w1.x = pk2(v2.x * sc, v2.y * sc); w1.y = pk2(v2.z * sc, v2.w * sc);
    w1.z = pk2(v3.x * sc, v3.y * sc); w1.w = pk2(v3.z * sc, v3.w * sc);
    ((uint4*)l)[0] = w0; ((uint4*)l)[1] = w1;
}

#define INV4PI 0.07957747154594767f

// ---------------------------------------------------------------------------
// Kernel 1: quantum encoding -> qevb (bf16 [B,H,E,S]) + K -> Kb (bf16
// [B,H,S,E]). One thread per token; ALL 16 value loads hoisted before the
// GEMV for 16-deep memory-level parallelism.
// ---------------------------------------------------------------------------
__global__ __launch_bounds__(64)
void qev3_kernel(const float* __restrict__ values,  // [B,S,H,E]
                 const float* __restrict__ key,     // [B,S,H,E]
                 const float* __restrict__ Wang, const float* __restrict__ bang,
                 const float* __restrict__ Wout, const float* __restrict__ bout,
                 unsigned short* __restrict__ qevb, // [B,H,E,S]
                 unsigned short* __restrict__ Kb)   // [B,H,S,E]
{
    __shared__ float sW[NP * EDIM];
    __shared__ float sWo[EDIM * 12];
    __shared__ float sba[NP];
    __shared__ float sbo[EDIM];

    const int tid = threadIdx.x;
    const int s0  = blockIdx.x * 64;
    const int h   = blockIdx.y;
    const int b   = blockIdx.z;

#pragma unroll
    for (int i = 0; i < 4; i++) ((float4*)sW)[i * 64 + tid] = ((const float4*)Wang)[i * 64 + tid];
#pragma unroll
    for (int i = 0; i < 3; i++) ((float4*)sWo)[i * 64 + tid] = ((const float4*)Wout)[i * 64 + tid];
    if (tid < NP) sba[tid] = bang[tid];
    sbo[tid] = bout[tid];
    __syncthreads();

    // ---- hoisted value loads (16 independent float4s) ----
    const float* vptr = values + ((size_t)(b * SS + s0 + tid) * HH + h) * EDIM;
    float4 vv[16];
#pragma unroll
    for (int c = 0; c < 16; c++) vv[c] = ((const float4*)vptr)[c];

    float ang[NP];
#pragma unroll
    for (int p = 0; p < NP; p++) ang[p] = sba[p];
#pragma unroll
    for (int c = 0; c < 16; c++) {
#pragma unroll
        for (int p = 0; p < NP; p++) {
            float a = ang[p];
            a = fmaf(sW[p * EDIM + c * 4 + 0], vv[c].x, a);
            a = fmaf(sW[p * EDIM + c * 4 + 1], vv[c].y, a);
            a = fmaf(sW[p * EDIM + c * 4 + 2], vv[c].z, a);
            a = fmaf(sW[p * EDIM + c * 4 + 3], vv[c].w, a);
            ang[p] = a;
        }
    }

    float sc[NP], cc[NP];
#pragma unroll
    for (int p = 0; p < NP; p++) {
        float u = ang[p] * INV4PI;
        sc[p] = __builtin_amdgcn_sinf(u);
        cc[p] = __builtin_amdgcn_cosf(u);
    }

    float sr[16], si[16];
#pragma unroll
    for (int i = 0; i < 16; i++) { sr[i] = 0.f; si[i] = 0.f; }
    sr[0] = 1.f;

    auto RY = [&](int w, float s, float c) {
        const int bit = 8 >> w;
#pragma unroll
        for (int i = 0; i < 16; i++) {
            if (!(i & bit)) {
                const int j = i | bit;
                float a0r = sr[i], a0i = si[i], a1r = sr[j], a1i = si[j];
                sr[i] = c * a0r - s * a1r;  si[i] = c * a0i - s * a1i;
                sr[j] = s * a0r + c * a1r;  si[j] = s * a0i + c * a1i;
            }
        }
    };
    auto CRX = [&](int cw, int tw, float s, float c) {
        const int cbit = 8 >> cw, tbit = 8 >> tw;
#pragma unroll
        for (int i = 0; i < 16; i++) {
            if ((i & cbit) && !(i & tbit)) {
                const int j = i | tbit;
                float a0r = sr[i], a0i = si[i], a1r = sr[j], a1i = si[j];
                sr[i] =  c * a0r + s * a1i;  si[i] =  c * a0i - s * a1r;
                sr[j] =  s * a0i + c * a1r;  si[j] = -s * a0r + c * a1i;
            }
        }
    };

    RY(0, sc[0], cc[0]); RY(1, sc[1], cc[1]); RY(2, sc[2], cc[2]); RY(3, sc[3], cc[3]);
    CRX(3, 0, sc[4], cc[4]); CRX(2, 3, sc[5], cc[5]); CRX(1, 2, sc[6], cc[6]); CRX(0, 1, sc[7], cc[7]);
    RY(0, sc[8], cc[8]); RY(1, sc[9], cc[9]); RY(2, sc[10], cc[10]); RY(3, sc[11], cc[11]);
    CRX(3, 2, sc[12], cc[12]); CRX(0, 3, sc[13], cc[13]); CRX(1, 0, sc[14], cc[14]); CRX(2, 1, sc[15], cc[15]);

    float meas[12];
#pragma unroll
    for (int w = 0; w < 4; w++) {
        const int bit = 8 >> w;
        float pr = 0.f, pi = 0.f, z = 0.f;
#pragma unroll
        for (int i = 0; i < 16; i++) {
            if (!(i & bit)) {
                const int j = i | bit;
                pr += sr[i] * sr[j] + si[i] * si[j];
                pi += sr[i] * si[j] - si[i] * sr[j];
                z  += sr[i] * sr[i] + si[i] * si[i] - sr[j] * sr[j] - si[j] * si[j];
            }
        }
        meas[w] = 2.f * pr; meas[4 + w] = 2.f * pi; meas[8 + w] = z;
    }

    unsigned short* ob = qevb + ((size_t)(b * HH + h) * EDIM) * SS + s0 + tid;
#pragma unroll
    for (int eb = 0; eb < 4; eb++) {
        float acc[16];
#pragma unroll
        for (int j = 0; j < 16; j++) acc[j] = sbo[eb * 16 + j];
#pragma unroll
        for (int mm = 0; mm < 12; mm++)
#pragma unroll
            for (int j = 0; j < 16; j++)
                acc[j] = fmaf(meas[mm], sWo[(eb * 16 + j) * 12 + mm], acc[j]);
#pragma unroll
        for (int j = 0; j < 16; j++)
            ob[(size_t)(eb * 16 + j) * SS] = f2bf(acc[j]);
    }

    // ---- K conversion: coalesced 512B writes per inst ----
    const float* ks = key + ((size_t)b * SS * HH + h) * EDIM;
    unsigned short* kd = Kb + ((size_t)(b * HH + h) * SS + s0) * EDIM;
#pragma unroll
    for (int i = 0; i < 16; i++) {
        const int u   = i * 64 + tid;
        const int row = u >> 4;
        const int ch  = u & 15;
        float4 v = *(const float4*)(ks + (size_t)(s0 + row) * HH * EDIM + ch * 4);
        uint2 w2; w2.x = pk2(v.x, v.y); w2.y = pk2(v.z, v.w);
        *(uint2*)&kd[row * EDIM + ch * 4] = w2;
    }
}

// ---------------------------------------------------------------------------
// Kernel 2: wave-owned-tile MFMA attention. Block = 4 waves, one causal pair
// (qt = bx, 31-bx). Wave w owns tiles t === w (mod 4) and computes ALL 64
// q-rows for them (partial O,l sum exactly -- no-max softmax is additive).
// Transposed matmuls: S^T = K*Q^T (A=K rows=s, B=Q rows=q), O^T = V^T*P^T
// (A=qevb rows=e, B=P in [q][s]). K/V fragments register-prefetched from
// global one own-tile ahead; NO barriers in the K-loop. Per-wave P buffer
// doubles as the bf16 O^T partial buffer for the cross-wave combine.
// ---------------------------------------------------------------------------
__global__ __launch_bounds__(256, 1)
void attn6_kernel(const float* __restrict__ qry,            // [B,L,H,E] fp32
                  const unsigned short* __restrict__ Kb,    // [B,H,S,E] bf16
                  const unsigned short* __restrict__ Vb,    // [B,H,E,S] bf16
                  float* __restrict__ out)                  // [B,L,H,E] fp32
{
    __shared__ unsigned short Qs[64 * LDP];
    __shared__ unsigned short Pq[4][64 * LDP];   // per-wave P[q][s] / O-partial[q][e]
    __shared__ float Lbuf[16 * 64];

    const int tid  = threadIdx.x;
    const int bx   = blockIdx.x;
    const int h    = blockIdx.y;
    const int b    = blockIdx.z;
    const int w    = tid >> 6;
    const int lane = tid & 63;
    const int ml   = lane & 15;
    const int quad = lane >> 4;
    const int srow = tid >> 2;
    const int sch  = tid & 3;

    const unsigned short* kbase = Kb + (size_t)(b * HH + h) * SS * EDIM;
    const unsigned short* vbase = Vb + (size_t)(b * HH + h) * EDIM * SS;
    unsigned short* Pw = &Pq[w][0];

    for (int pass = 0; pass < 2; ++pass) {
        const int qt = pass ? (NQT - 1 - bx) : bx;
        const int q0 = qt * 64;

        __syncthreads();   // prev pass readers done with Qs/Pq
        stage16s(qry + (((size_t)b * LL + q0 + srow) * HH + h) * EDIM + sch * 16,
                 &Qs[srow * LDP + sch * 16], 0.125f);
        __syncthreads();

        // Q B-fragments (rows = q), loop-invariant
        bf16x8 bq[4][2];
#pragma unroll
        for (int ntq = 0; ntq < 4; ntq++) {
            bq[ntq][0] = *(const bf16x8*)&Qs[(16 * ntq + ml) * LDP + quad * 8];
            bq[ntq][1] = *(const bf16x8*)&Qs[(16 * ntq + ml) * LDP + quad * 8 + 32];
        }

        f32x4 oaccT[4][4];    // [mte][ntq]: O^T[e][q]
        float lacc[4] = {0.f, 0.f, 0.f, 0.f};
#pragma unroll
        for (int i = 0; i < 4; i++)
#pragma unroll
            for (int j = 0; j < 4; j++) oaccT[i][j] = (f32x4)(0.f);

        int t = w;
        uint4 kc[8], vc[8];
        if (t <= qt) {
#pragma unroll
            for (int f = 0; f < 8; f++) {
                const int mt = f >> 1, hf = f & 1;
                kc[f] = *(const uint4*)(kbase + (size_t)(t * 64 + 16 * mt + ml) * EDIM + quad * 8 + 32 * hf);
                vc[f] = *(const uint4*)(vbase + (size_t)(16 * mt + ml) * SS + t * 64 + quad * 8 + 32 * hf);
            }
        }

        for (; t <= qt; t += 4) {
            uint4 kn[8], vn[8];
            const bool more = (t + 4 <= qt);
            if (more) {
#pragma unroll
                for (int f = 0; f < 8; f++) {
                    const int mt = f >> 1, hf = f & 1;
                    kn[f] = *(const uint4*)(kbase + (size_t)((t + 4) * 64 + 16 * mt + ml) * EDIM + quad * 8 + 32 * hf);
                    vn[f] = *(const uint4*)(vbase + (size_t)(16 * mt + ml) * SS + (t + 4) * 64 + quad * 8 + 32 * hf);
                }
            }
            const bool diag = (t == qt);

            // ---- S^T = K*Q^T, exp, b64-pack into Pw[q][s] ----
#pragma unroll
            for (int mts = 0; mts < 4; mts++)
#pragma unroll
                for (int ntq = 0; ntq < 4; ntq++) {
                    f32x4 s = __builtin_amdgcn_mfma_f32_16x16x32_bf16(
                        *(const bf16x8*)&kc[2 * mts], bq[ntq][0], (f32x4)(0.f), 0, 0, 0);
                    s = __builtin_amdgcn_mfma_f32_16x16x32_bf16(
                        *(const bf16x8*)&kc[2 * mts + 1], bq[ntq][1], s, 0, 0, 0);
                    float p0 = __expf(s[0]), p1 = __expf(s[1]), p2 = __expf(s[2]), p3 = __expf(s[3]);
                    if (diag) {
                        const int sbase = 16 * mts + 4 * quad, qcol = 16 * ntq + ml;
                        if (sbase + 0 > qcol) p0 = 0.f;
                        if (sbase + 1 > qcol) p1 = 0.f;
                        if (sbase + 2 > qcol) p2 = 0.f;
                        if (sbase + 3 > qcol) p3 = 0.f;
                    }
                    lacc[ntq] += (p0 + p1) + (p2 + p3);
                    uint2 u; u.x = tpk2(p0, p1); u.y = tpk2(p2, p3);
                    *(uint2*)&Pw[(16 * ntq + ml) * LDP + 16 * mts + 4 * quad] = u;
                }

            // ---- O^T += V^T * P^T (B-frags from Pw rows=q) ----
#pragma unroll
            for (int ntq = 0; ntq < 4; ntq++) {
                bf16x8 pb0 = *(const bf16x8*)&Pw[(16 * ntq + ml) * LDP + quad * 8];
                bf16x8 pb1 = *(const bf16x8*)&Pw[(16 * ntq + ml) * LDP + quad * 8 + 32];
#pragma unroll
                for (int mte = 0; mte < 4; mte++) {
                    oaccT[mte][ntq] = __builtin_amdgcn_mfma_f32_16x16x32_bf16(
                        *(const bf16x8*)&vc[2 * mte], pb0, oaccT[mte][ntq], 0, 0, 0);
                    oaccT[mte][ntq] = __builtin_amdgcn_mfma_f32_16x16x32_bf16(
                        *(const bf16x8*)&vc[2 * mte + 1], pb1, oaccT[mte][ntq], 0, 0, 0);
                }
            }

            if (more) {
#pragma unroll
                for (int f = 0; f < 8; f++) { kc[f] = kn[f]; vc[f] = vn[f]; }
            }
        }

        // ---- write partials: O^T (bf16, stored as [q][e] rows) + l ----
#pragma unroll
        for (int mte = 0; mte < 4; mte++)
#pragma unroll
            for (int ntq = 0; ntq < 4; ntq++) {
                uint2 u;
                u.x = pk2(oaccT[mte][ntq][0], oaccT[mte][ntq][1]);
                u.y = pk2(oaccT[mte][ntq][2], oaccT[mte][ntq][3]);
                *(uint2*)&Pw[(16 * ntq + ml) * LDP + 16 * mte + 4 * quad] = u;
            }
#pragma unroll
        for (int ntq = 0; ntq < 4; ntq++)
            Lbuf[(w * 4 + quad) * 64 + 16 * ntq + ml] = lacc[ntq];

        __syncthreads();

        // ---- reduce 4 partials, normalize, store fp32 float4 ----
        {
            const int q = tid >> 2, c = tid & 3;
            float lsum = 0.f;
#pragma unroll
            for (int i = 0; i < 16; i++) lsum += Lbuf[i * 64 + q];
            const float inv = 1.f / lsum;
            float* orow = out + (((size_t)b * LL + q0 + q) * HH + h) * EDIM;
#pragma unroll
            for (int c4 = 0; c4 < 4; c4++) {
                const int e0 = c * 16 + c4 * 4;
                float a0 = 0.f, a1 = 0.f, a2 = 0.f, a3 = 0.f;
#pragma unroll
                for (int wv = 0; wv < 4; wv++) {
                    uint2 u = *(const uint2*)&Pq[wv][q * LDP + e0];
                    a0 += bf2f(u.x & 0xffffu); a1 += bf2f(u.x >> 16);
                    a2 += bf2f(u.y & 0xffffu); a3 += bf2f(u.y >> 16);
                }
                float4 r; r.x = a0 * inv; r.y = a1 * inv; r.z = a2 * inv; r.w = a3 * inv;
                *(float4*)&orow[e0] = r;
            }
        }
    }
}

extern "C" void kernel_launch(void* const* d_in, const int* in_sizes, int n_in,
                              void* d_out, int out_size, void* d_ws, size_t ws_size,
                              hipStream_t stream)
{
    const float* qry  = (const float*)d_in[0];
    const float* key  = (const float*)d_in[1];
    const float* val  = (const float*)d_in[2];
    const float* Wang = (const float*)d_in[3];
    const float* bang = (const float*)d_in[4];
    const float* Wout = (const float*)d_in[5];
    const float* bout = (const float*)d_in[6];
    float* out = (float*)d_out;

    unsigned short* qevb = (unsigned short*)d_ws;                                             // 4 MB
    unsigned short* Kb   = (unsigned short*)((char*)d_ws + (size_t)BB * HH * EDIM * SS * 2);  // 4 MB

    (void)in_sizes; (void)n_in; (void)out_size; (void)ws_size;

    qev3_kernel<<<dim3(SS / 64, HH, BB), 64, 0, stream>>>(val, key, Wang, bang, Wout, bout, qevb, Kb);
    attn6_kernel<<<dim3(NPAIR, HH, BB), 256, 0, stream>>>(qry, Kb, qevb, out);
}